// Round 6
// baseline (1033.017 us; speedup 1.0000x reference)
//
#include <hip/hip_runtime.h>
#include <hip/hip_bf16.h>
#include <hip/hip_fp16.h>

// Problem constants
#define B_N 32
#define S_N 2048
#define E_N 256
#define H_N 256
#define K2_N 512            // 2E
#define N3_N 768            // 3H
#define M_N (B_N * S_N)     // 65536 rows
#define CCH 16              // scan chunks per sequence
#define LCH (S_N / CCH)     // 128 steps per chunk

typedef __hip_bfloat16 bf16;
typedef __attribute__((ext_vector_type(8))) short bf16x8s;
typedef __attribute__((ext_vector_type(4))) float f32x4;

#define BM 128
#define BN 128
#define BK 32
#define LDT (BK + 8)

// R5 post-mortem: 4x bit-identical absmax across MFMA orientations, probe-
// recovered maps, scan structures, and f-plane dtypes => compute pipeline is
// self-consistent; bug was at an interface. Harness contract: d_out dtype =
// reference OUTPUT dtype = float32 ("bf16" in the test label is the hardcoded
// threshold convention, not the buffer dtype). R6: all outputs written fp32.

__device__ __forceinline__ float sigmoid_fast(float v) {
    return 1.0f / (1.0f + __expf(-v));
}
__device__ __forceinline__ float tanh_fast(float v) {
    return 2.0f / (1.0f + __expf(-2.0f * v)) - 1.0f;
}
__device__ __forceinline__ short bf16_bits(float v) {
    bf16 b = __float2bfloat16(v);
    return *(short*)&b;
}

// Runtime input-dtype vote (fp32 vs bf16), wave-uniform.
__device__ __forceinline__ bool inputs_are_fp32(const void* xp) {
    const unsigned short* xb = (const unsigned short*)xp;
    int lane = threadIdx.x & 63;
    unsigned u0 = xb[lane * 2];
    unsigned u1 = xb[lane * 2 + 1];
    int e0 = (u0 >> 7) & 0xFF;
    int e1 = (u1 >> 7) & 0xFF;
    int ok = (e0 >= 97 && e0 <= 140) && (e1 >= 97 && e1 <= 140);
    unsigned long long m = __ballot(ok);
    return __popcll(m) < 56;
}

__global__ __launch_bounds__(256) void gemm_act(
    const void* __restrict__ xv, const void* __restrict__ Wv,
    const void* __restrict__ bv,
    bf16* __restrict__ Zp, __half* __restrict__ Fh, float* __restrict__ Oout)
{
    __shared__ bf16 As[BM][LDT];   // [m][k]
    __shared__ bf16 Bs[BN][LDT];   // [n][k]

    const int tid  = threadIdx.x;
    const int lane = tid & 63;
    const int wave = tid >> 6;
    const int wm   = (wave & 1) * 64;
    const int wn   = (wave >> 1) * 64;
    const int l15  = lane & 15;
    const int quad = lane >> 4;
    const int r0   = blockIdx.x * BM;
    const int n0   = blockIdx.y * BN;

    const bool is32 = inputs_are_fp32(xv);

    // ---- runtime C/D layout recovery probe (validated R5: matches m89 map) ----
    bf16x8s pa = {}, pb = {}, oa = {}, ob = {};
    if (quad == 0) {
        pa[0] = bf16_bits((float)(l15 + 1));   // A[m][0] = m+1
        pb[0] = bf16_bits((float)(l15 + 1));   // B[0][n] = n+1
        oa[0] = bf16_bits(1.0f);
        ob[0] = bf16_bits(1.0f);
    }
    f32x4 zero4 = {0.f, 0.f, 0.f, 0.f};
    f32x4 d1 = __builtin_amdgcn_mfma_f32_16x16x32_bf16(pa, ob, zero4, 0, 0, 0); // row+1
    f32x4 d2 = __builtin_amdgcn_mfma_f32_16x16x32_bf16(oa, pb, zero4, 0, 0, 0); // col+1
    f32x4 d3 = __builtin_amdgcn_mfma_f32_16x16x32_bf16(pa, pb, zero4, 0, 0, 0); // (r+1)(c+1)
    int row_j[4], col_j[4];
    int okp = 1;
    #pragma unroll
    for (int j = 0; j < 4; ++j) {
        float rv = d1[j], cv = d2[j];
        int ri = (int)rv - 1, ci = (int)cv - 1;
        okp &= (rv == floorf(rv)) & (cv == floorf(cv));
        okp &= (ri >= 0) & (ri < 16) & (ci >= 0) & (ci < 16);
        okp &= (d3[j] == rv * cv);
        row_j[j] = ri; col_j[j] = ci;
    }
    unsigned long long mok = __ballot(okp);
    const bool use_mfma = (mok == ~0ull);
    if (!use_mfma) {
        #pragma unroll
        for (int j = 0; j < 4; ++j) { row_j[j] = l15; col_j[j] = quad * 4 + j; }
    }

    f32x4 acc[4][4] = {};

    for (int kt = 0; kt < K2_N / BK; ++kt) {
        const int k0 = kt * BK;
        __syncthreads();
        // --- stage A tile ---
        #pragma unroll
        for (int i = 0; i < 2; ++i) {
            int q   = tid + i * 256;
            int row = q >> 2;
            int k   = (q & 3) * 8;
            int r   = r0 + row;
            bool zero_row = (k0 >= E_N) && ((r & (S_N - 1)) == 0);
            size_t off = (k0 < E_N) ? ((size_t)r * E_N + (k0 + k))
                                    : ((size_t)(r - 1) * E_N + (k0 - E_N + k));
            if (is32) {
                float vals[8];
                if (zero_row) {
                    #pragma unroll
                    for (int j = 0; j < 8; ++j) vals[j] = 0.f;
                } else {
                    const float* p = (const float*)xv + off;
                    *(float4*)(vals)     = *(const float4*)(p);
                    *(float4*)(vals + 4) = *(const float4*)(p + 4);
                }
                bf16 t[8];
                #pragma unroll
                for (int j = 0; j < 8; ++j) t[j] = __float2bfloat16(vals[j]);
                *(int4*)(&As[row][k]) = *(int4*)t;
            } else {
                int4 val;
                if (zero_row) val = make_int4(0, 0, 0, 0);
                else          val = *(const int4*)((const bf16*)xv + off);
                *(int4*)(&As[row][k]) = val;
            }
        }
        // --- stage B tile (W row-major [512][768]) into Bs[n][k] ---
        #pragma unroll
        for (int i = 0; i < 4; ++i) {
            int q = tid + i * 256;
            int n = q & 127;
            int k = (q >> 7) * 4;
            #pragma unroll
            for (int j = 0; j < 4; ++j) {
                float w = is32 ? ((const float*)Wv)[(size_t)(k0 + k + j) * N3_N + (n0 + n)]
                               : __bfloat162float(((const bf16*)Wv)[(size_t)(k0 + k + j) * N3_N + (n0 + n)]);
                Bs[n][k + j] = __float2bfloat16(w);
            }
        }
        __syncthreads();

        if (use_mfma) {
            bf16x8s a_frag[4], b_frag[4];
            #pragma unroll
            for (int mi = 0; mi < 4; ++mi)
                a_frag[mi] = *(const bf16x8s*)(&As[wm + mi * 16 + l15][quad * 8]);
            #pragma unroll
            for (int ni = 0; ni < 4; ++ni)
                b_frag[ni] = *(const bf16x8s*)(&Bs[wn + ni * 16 + l15][quad * 8]);
            #pragma unroll
            for (int mi = 0; mi < 4; ++mi)
                #pragma unroll
                for (int ni = 0; ni < 4; ++ni)
                    acc[mi][ni] = __builtin_amdgcn_mfma_f32_16x16x32_bf16(
                        a_frag[mi], b_frag[ni], acc[mi][ni], 0, 0, 0);
        } else {
            for (int mi = 0; mi < 4; ++mi) {
                int rr = wm + mi * 16 + l15;
                for (int ni = 0; ni < 4; ++ni) {
                    for (int jj = 0; jj < 4; ++jj) {
                        int cc2 = wn + ni * 16 + quad * 4 + jj;
                        float s = acc[mi][ni][jj];
                        #pragma unroll 1
                        for (int k = 0; k < BK; ++k)
                            s += __bfloat162float(As[rr][k]) * __bfloat162float(Bs[cc2][k]);
                        acc[mi][ni][jj] = s;
                    }
                }
            }
        }
    }

    // --- epilogue: bias + activation; z->bf16 ws, f->fp16 ws, o->fp32 out ---
    const int type = n0 >> 8;                 // 0=z(tanh), 1=f(sig), 2=o(sig)
    #pragma unroll
    for (int mi = 0; mi < 4; ++mi) {
        #pragma unroll
        for (int ni = 0; ni < 4; ++ni) {
            #pragma unroll
            for (int j = 0; j < 4; ++j) {
                int r    = r0 + wm + mi * 16 + row_j[j];
                int colg = n0 + wn + ni * 16 + col_j[j];
                int col  = colg - type * 256;
                float bias = is32 ? ((const float*)bv)[colg]
                                  : __bfloat162float(((const bf16*)bv)[colg]);
                float v = acc[mi][ni][j] + bias;
                if (type == 0)
                    Zp[(size_t)r * H_N + col] = __float2bfloat16(tanh_fast(v));
                else if (type == 1)
                    Fh[(size_t)r * H_N + col] = __float2half(sigmoid_fast(v));
                else
                    Oout[(size_t)r * H_N + col] = sigmoid_fast(v);   // fp32 stage
            }
        }
    }
}

// K2: per-chunk local scan from c=0
__global__ __launch_bounds__(256) void scan_part1(
    const bf16* __restrict__ Zp, const __half* __restrict__ Fh,
    float* __restrict__ Cend, float* __restrict__ Pprod)
{
    int bc = blockIdx.x;
    int h  = threadIdx.x;
    size_t base = (size_t)bc * LCH * H_N + h;
    float c = 0.f, P = 1.f;
    for (int t = 0; t < LCH; ++t) {
        float z = __bfloat162float(Zp[base]);
        float f = __half2float(Fh[base]);
        c = f * c + (1.f - f) * z;
        P *= f;
        base += H_N;
    }
    Cend[(size_t)bc * H_N + h]  = c;
    Pprod[(size_t)bc * H_N + h] = P;
}

// K3: sequential scan across chunks
__global__ __launch_bounds__(256) void scan_part2(
    const float* __restrict__ Cend, const float* __restrict__ Pprod,
    float* __restrict__ Cstart)
{
    int b = blockIdx.x;
    int h = threadIdx.x;
    float cs = 0.f;
    for (int ch = 0; ch < CCH; ++ch) {
        size_t idx = (size_t)(b * CCH + ch) * H_N + h;
        Cstart[idx] = cs;
        cs = Cend[idx] + Pprod[idx] * cs;
    }
}

// K4: replay chunk; o staged fp32 in outH, overwritten with fp32 h in-place.
__global__ __launch_bounds__(256) void scan_part3(
    const bf16* __restrict__ Zp, const __half* __restrict__ Fh,
    const float* __restrict__ Cstart, const int* __restrict__ mask,
    float* __restrict__ outH, float* __restrict__ outHid, float* __restrict__ outCell)
{
    int bc = blockIdx.x;
    int b  = bc >> 4;
    int h  = threadIdx.x;
    float c = Cstart[(size_t)bc * H_N + h];
    int tgt = mask[b] - 1;
    tgt = (tgt < 0) ? 0 : ((tgt > S_N - 1) ? (S_N - 1) : tgt);
    int s0 = (bc & (CCH - 1)) * LCH;
    size_t base = (size_t)bc * LCH * H_N + h;
    for (int t = 0; t < LCH; ++t) {
        float z = __bfloat162float(Zp[base]);
        float f = __half2float(Fh[base]);
        float o = outH[base];
        c = f * c + (1.f - f) * z;
        float hv = o * c;
        outH[base] = hv;
        if (s0 + t == tgt) {
            outHid[(size_t)b * H_N + h]  = hv;
            outCell[(size_t)b * H_N + h] = c;
        }
        base += H_N;
    }
}

// Serial-scan fallback (used when ws too small for chunk-state arrays)
__global__ __launch_bounds__(64) void scan_serial(
    const bf16* __restrict__ Zp, const __half* __restrict__ Fh,
    const int* __restrict__ mask,
    float* __restrict__ outH, float* __restrict__ outHid, float* __restrict__ outCell)
{
    int b = blockIdx.x >> 2;
    int h = (blockIdx.x & 3) * 64 + threadIdx.x;
    int tgt = mask[b] - 1;
    tgt = (tgt < 0) ? 0 : ((tgt > S_N - 1) ? (S_N - 1) : tgt);
    size_t base = (size_t)b * S_N * H_N + h;
    float c = 0.f;
    for (int t = 0; t < S_N; ++t) {
        float z = __bfloat162float(Zp[base]);
        float f = __half2float(Fh[base]);
        float o = outH[base];
        c = f * c + (1.f - f) * z;
        float hv = o * c;
        outH[base] = hv;
        if (t == tgt) {
            outHid[(size_t)b * H_N + h]  = hv;
            outCell[(size_t)b * H_N + h] = c;
        }
        base += H_N;
    }
}

extern "C" void kernel_launch(void* const* d_in, const int* in_sizes, int n_in,
                              void* d_out, int out_size, void* d_ws, size_t ws_size,
                              hipStream_t stream) {
    // Resolve inputs by element count: x=16777216, mask=32, W=393216, b=768.
    const void* x = nullptr; const int* mask = nullptr;
    const void* W = nullptr; const void* bvec = nullptr;
    for (int i = 0; i < n_in; ++i) {
        switch (in_sizes[i]) {
            case M_N * E_N:     x    = d_in[i]; break;
            case B_N:           mask = (const int*)d_in[i]; break;
            case K2_N * N3_N:   W    = d_in[i]; break;
            case N3_N:          bvec = d_in[i]; break;
        }
    }

    float* out     = (float*)d_out;                     // hidden_temp [B,S,H] fp32 (o staging)
    float* outHid  = out + (size_t)M_N * H_N;           // hidden [B,1,H]
    float* outCell = outHid + (size_t)B_N * H_N;        // cell_state [B,1,H]

    // ws: z bf16 (32MiB) + f fp16 (32MiB) [+ 1.5MiB chunk-scan state if it fits]
    bf16*   Zp = (bf16*)d_ws;
    __half* Fh = (__half*)(Zp + (size_t)M_N * H_N);
    float* Cend   = (float*)(Fh + (size_t)M_N * H_N);
    float* Pprod  = Cend + (size_t)B_N * CCH * H_N;
    float* Cstart = Pprod + (size_t)B_N * CCH * H_N;
    size_t need_chunked = (size_t)M_N * H_N * 4 + (size_t)B_N * CCH * H_N * 12;

    dim3 g1(M_N / BM, N3_N / BN);   // 512 x 6
    gemm_act<<<g1, 256, 0, stream>>>(x, W, bvec, Zp, Fh, out);
    if (ws_size >= need_chunked) {
        scan_part1<<<B_N * CCH, 256, 0, stream>>>(Zp, Fh, Cend, Pprod);
        scan_part2<<<B_N, 256, 0, stream>>>(Cend, Pprod, Cstart);
        scan_part3<<<B_N * CCH, 256, 0, stream>>>(Zp, Fh, Cstart, mask, out, outHid, outCell);
    } else {
        scan_serial<<<B_N * 4, 64, 0, stream>>>(Zp, Fh, mask, out, outHid, outCell);
    }
}

// Round 7
// 280.717 us; speedup vs baseline: 3.6799x; 3.6799x over previous
//
#include <hip/hip_runtime.h>
#include <hip/hip_bf16.h>
#include <hip/hip_fp16.h>

// Problem constants
#define B_N 32
#define S_N 2048
#define E_N 256
#define H_N 256
#define K2_N 512            // 2E
#define N3_N 768            // 3H
#define M_N (B_N * S_N)     // 65536 rows
#define CCH 16              // scan chunks per sequence
#define LCH (S_N / CCH)     // 128 steps per chunk

typedef __hip_bfloat16 bf16;
typedef __attribute__((ext_vector_type(8))) short bf16x8s;
typedef __attribute__((ext_vector_type(4))) float f32x4;

#define BM 128
#define BN 128
#define BK 32

#define GLOBAL_AS __attribute__((address_space(1)))
#define LDS_AS    __attribute__((address_space(3)))

// R6 post-mortem: PASS at 1033us. gemm_act 913us, MfmaUtil 2.3% == 56TF ==
// latency-bound staging (scalar W loads + fp32 cvt in-loop). R7: pre-convert
// x->bf16 (+zero guard row) and W->bf16 transposed; GEMM staged via
// global_load_lds width=16 (m97 pattern). Probe/fallback/vote dropped:
// canonical C/D map (row=quad*4+reg, col=lane&15) HW-confirmed by R6 pass.
// Inputs fp32 confirmed (R1 NaN signature + R6 pass). Output fp32 confirmed.

__device__ __forceinline__ float sigmoid_fast(float v) {
    return 1.0f / (1.0f + __expf(-v));
}
__device__ __forceinline__ float tanh_fast(float v) {
    return 2.0f / (1.0f + __expf(-2.0f * v)) - 1.0f;
}

// K0a: x fp32 -> xb bf16; also zeroes the 256-element guard row before xb
// (so x_prev reads at r==-1 see zeros).
__global__ __launch_bounds__(256) void convert_x(
    const float* __restrict__ x, bf16* __restrict__ xb)
{
    if (blockIdx.x == 0 && threadIdx.x < 32) {
        bf16 z[8] = {};
        *(int4*)(xb - 256 + threadIdx.x * 8) = *(int4*)z;
    }
    size_t i = ((size_t)blockIdx.x * 256 + threadIdx.x) * 8;
    float4 v0 = *(const float4*)(x + i);
    float4 v1 = *(const float4*)(x + i + 4);
    bf16 t[8];
    t[0] = __float2bfloat16(v0.x); t[1] = __float2bfloat16(v0.y);
    t[2] = __float2bfloat16(v0.z); t[3] = __float2bfloat16(v0.w);
    t[4] = __float2bfloat16(v1.x); t[5] = __float2bfloat16(v1.y);
    t[6] = __float2bfloat16(v1.z); t[7] = __float2bfloat16(v1.w);
    *(int4*)(xb + i) = *(int4*)t;
}

// K0b: W fp32 [512][768] -> Wt bf16 [768][512] via LDS 64x64 tile transpose.
__global__ __launch_bounds__(256) void transpose_w(
    const float* __restrict__ W, bf16* __restrict__ Wt)
{
    __shared__ bf16 tile[64][65];
    const int k0 = blockIdx.x * 64;          // 0..448
    const int n0 = blockIdx.y * 64;          // 0..704
    const int t  = threadIdx.x;
    const int tr = t >> 6;                   // 0..3
    const int tc = t & 63;
    #pragma unroll
    for (int p = 0; p < 16; ++p) {
        int kk = tr + p * 4;
        tile[kk][tc] = __float2bfloat16(W[(size_t)(k0 + kk) * N3_N + n0 + tc]);
    }
    __syncthreads();
    #pragma unroll
    for (int p = 0; p < 16; ++p) {
        int nn = tr + p * 4;
        Wt[(size_t)(n0 + nn) * K2_N + k0 + tc] = tile[tc][nn];
    }
}

// K1: gates GEMM (m97-style async staging) + bias + activation.
// z -> bf16 ws, f -> fp16 ws, o -> fp32 out (hidden_temp region).
__global__ __launch_bounds__(256) void gemm_act(
    const bf16* __restrict__ xb, const bf16* __restrict__ Wt,
    const float* __restrict__ bvec,
    bf16* __restrict__ Zp, __half* __restrict__ Fh, float* __restrict__ Oout)
{
    __shared__ bf16 As[BM][BK];   // unpadded: global_load_lds needs lane-contiguous dest
    __shared__ bf16 Bs[BN][BK];

    const int tid  = threadIdx.x;
    const int lane = tid & 63;
    const int wave = tid >> 6;
    const int wm   = (wave & 1) * 64;
    const int wn   = (wave >> 1) * 64;
    const int l15  = lane & 15;
    const int quad = lane >> 4;
    const int l4   = lane >> 2;      // chunk row 0..15
    const int q4   = lane & 3;       // k-quarter 0..3
    const int r0   = blockIdx.x * BM;
    const int n0   = blockIdx.y * BN;
    const bool zfix = ((r0 & (S_N - 1)) == 0);  // block row 0 has s==0

    f32x4 acc[4][4] = {};

    for (int kt = 0; kt < K2_N / BK; ++kt) {
        const int k0 = kt * BK;
        const bool second = (k0 >= E_N);   // x_{t-1} half
        __syncthreads();
        // --- async global->LDS staging: each wave 2 A-chunks + 2 B-chunks ---
        // chunk c = 16 rows x 32 k = 1 KiB; lane l -> row c*16+l/4, k-qtr l%4.
        #pragma unroll
        for (int cc = 0; cc < 2; ++cc) {
            int c   = wave + cc * 4;
            int row = c * 16 + l4;
            int rA  = r0 + row - (second ? 1 : 0);
            const bf16* ga = xb + (size_t)rA * E_N + (k0 & (E_N - 1)) + q4 * 8;
            __builtin_amdgcn_global_load_lds(
                (const GLOBAL_AS void*)ga,
                (LDS_AS void*)&As[c * 16][0], 16, 0, 0);
            const bf16* gb = Wt + (size_t)(n0 + row) * K2_N + k0 + q4 * 8;
            __builtin_amdgcn_global_load_lds(
                (const GLOBAL_AS void*)gb,
                (LDS_AS void*)&Bs[c * 16][0], 16, 0, 0);
        }
        __syncthreads();
        if (second && zfix) {
            // global row r0 has s==0: x_prev must be zero (we staged xb[r0-1])
            if (tid < 4) {
                bf16 zz[8] = {};
                *(int4*)(&As[0][tid * 8]) = *(int4*)zz;
            }
            __syncthreads();
        }
        // --- fragments + MFMA (canonical orientation, HW-confirmed R6) ---
        bf16x8s a_frag[4], b_frag[4];
        #pragma unroll
        for (int mi = 0; mi < 4; ++mi)
            a_frag[mi] = *(const bf16x8s*)(&As[wm + mi * 16 + l15][quad * 8]);
        #pragma unroll
        for (int ni = 0; ni < 4; ++ni)
            b_frag[ni] = *(const bf16x8s*)(&Bs[wn + ni * 16 + l15][quad * 8]);
        #pragma unroll
        for (int mi = 0; mi < 4; ++mi)
            #pragma unroll
            for (int ni = 0; ni < 4; ++ni)
                acc[mi][ni] = __builtin_amdgcn_mfma_f32_16x16x32_bf16(
                    a_frag[mi], b_frag[ni], acc[mi][ni], 0, 0, 0);
    }

    // --- epilogue: D row = quad*4+reg (x-row), D col = l15 (gate col) ---
    const int type = n0 >> 8;                 // 0=z(tanh), 1=f(sig), 2=o(sig)
    #pragma unroll
    for (int ni = 0; ni < 4; ++ni) {
        int colg = n0 + wn + ni * 16 + l15;
        int col  = colg - type * 256;
        float bias = bvec[colg];
        #pragma unroll
        for (int mi = 0; mi < 4; ++mi) {
            #pragma unroll
            for (int j = 0; j < 4; ++j) {
                int r = r0 + wm + mi * 16 + quad * 4 + j;
                float v = acc[mi][ni][j] + bias;
                if (type == 0)
                    Zp[(size_t)r * H_N + col] = __float2bfloat16(tanh_fast(v));
                else if (type == 1)
                    Fh[(size_t)r * H_N + col] = __float2half(sigmoid_fast(v));
                else
                    Oout[(size_t)r * H_N + col] = sigmoid_fast(v);
            }
        }
    }
}

// K2: per-chunk local scan from c=0
__global__ __launch_bounds__(256) void scan_part1(
    const bf16* __restrict__ Zp, const __half* __restrict__ Fh,
    float* __restrict__ Cend, float* __restrict__ Pprod)
{
    int bc = blockIdx.x;
    int h  = threadIdx.x;
    size_t base = (size_t)bc * LCH * H_N + h;
    float c = 0.f, P = 1.f;
    for (int t = 0; t < LCH; ++t) {
        float z = __bfloat162float(Zp[base]);
        float f = __half2float(Fh[base]);
        c = f * c + (1.f - f) * z;
        P *= f;
        base += H_N;
    }
    Cend[(size_t)bc * H_N + h]  = c;
    Pprod[(size_t)bc * H_N + h] = P;
}

// K3: sequential scan across chunks
__global__ __launch_bounds__(256) void scan_part2(
    const float* __restrict__ Cend, const float* __restrict__ Pprod,
    float* __restrict__ Cstart)
{
    int b = blockIdx.x;
    int h = threadIdx.x;
    float cs = 0.f;
    for (int ch = 0; ch < CCH; ++ch) {
        size_t idx = (size_t)(b * CCH + ch) * H_N + h;
        Cstart[idx] = cs;
        cs = Cend[idx] + Pprod[idx] * cs;
    }
}

// K4: replay chunk; o staged fp32 in outH, overwritten with fp32 h in-place.
__global__ __launch_bounds__(256) void scan_part3(
    const bf16* __restrict__ Zp, const __half* __restrict__ Fh,
    const float* __restrict__ Cstart, const int* __restrict__ mask,
    float* __restrict__ outH, float* __restrict__ outHid, float* __restrict__ outCell)
{
    int bc = blockIdx.x;
    int b  = bc >> 4;
    int h  = threadIdx.x;
    float c = Cstart[(size_t)bc * H_N + h];
    int tgt = mask[b] - 1;
    tgt = (tgt < 0) ? 0 : ((tgt > S_N - 1) ? (S_N - 1) : tgt);
    int s0 = (bc & (CCH - 1)) * LCH;
    size_t base = (size_t)bc * LCH * H_N + h;
    for (int t = 0; t < LCH; ++t) {
        float z = __bfloat162float(Zp[base]);
        float f = __half2float(Fh[base]);
        float o = outH[base];
        c = f * c + (1.f - f) * z;
        float hv = o * c;
        outH[base] = hv;
        if (s0 + t == tgt) {
            outHid[(size_t)b * H_N + h]  = hv;
            outCell[(size_t)b * H_N + h] = c;
        }
        base += H_N;
    }
}

extern "C" void kernel_launch(void* const* d_in, const int* in_sizes, int n_in,
                              void* d_out, int out_size, void* d_ws, size_t ws_size,
                              hipStream_t stream) {
    // Resolve inputs by element count: x=16777216, mask=32, W=393216, b=768.
    const float* x = nullptr; const int* mask = nullptr;
    const float* W = nullptr; const float* bvec = nullptr;
    for (int i = 0; i < n_in; ++i) {
        switch (in_sizes[i]) {
            case M_N * E_N:     x    = (const float*)d_in[i]; break;
            case B_N:           mask = (const int*)d_in[i]; break;
            case K2_N * N3_N:   W    = (const float*)d_in[i]; break;
            case N3_N:          bvec = (const float*)d_in[i]; break;
        }
    }

    float* out     = (float*)d_out;                     // hidden_temp [B,S,H] fp32 (o staging)
    float* outHid  = out + (size_t)M_N * H_N;           // hidden [B,1,H]
    float* outCell = outHid + (size_t)B_N * H_N;        // cell_state [B,1,H]

    // ws layout (ws >= 129.5 MiB proven R2/R3 identity):
    // [512B guard][xb 32MiB][Wt 0.75MiB][Zp 32MiB][Fh 32MiB][state 1.5MiB]
    bf16*   xb = (bf16*)d_ws + 256;                     // guard row before xb
    bf16*   Wt = xb + (size_t)M_N * E_N;
    bf16*   Zp = Wt + (size_t)N3_N * K2_N;
    __half* Fh = (__half*)(Zp + (size_t)M_N * H_N);
    float* Cend   = (float*)(Fh + (size_t)M_N * H_N);
    float* Pprod  = Cend + (size_t)B_N * CCH * H_N;
    float* Cstart = Pprod + (size_t)B_N * CCH * H_N;

    convert_x<<<M_N * E_N / (256 * 8), 256, 0, stream>>>(x, xb);
    transpose_w<<<dim3(K2_N / 64, N3_N / 64), 256, 0, stream>>>(W, Wt);

    dim3 g1(M_N / BM, N3_N / BN);   // 512 x 6
    gemm_act<<<g1, 256, 0, stream>>>(xb, Wt, bvec, Zp, Fh, out);
    scan_part1<<<B_N * CCH, 256, 0, stream>>>(Zp, Fh, Cend, Pprod);
    scan_part2<<<B_N, 256, 0, stream>>>(Cend, Pprod, Cstart);
    scan_part3<<<B_N * CCH, 256, 0, stream>>>(Zp, Fh, Cstart, mask, out, outHid, outCell);
}